// Round 7
// baseline (609.872 us; speedup 1.0000x reference)
//
#include <hip/hip_runtime.h>
#include <hip/hip_bf16.h>
#include <stdint.h>

#define FDIM   1024
#define NCLS   100
#define CDIM   512
#define NBATCH 4096

typedef __attribute__((ext_vector_type(8))) short short8;
typedef __attribute__((ext_vector_type(4))) float f32x4;

typedef const __attribute__((address_space(1))) unsigned int guint;
typedef __attribute__((address_space(3))) unsigned int luint;

__device__ __forceinline__ void gl_lds16(const unsigned short* g, unsigned short* l) {
    __builtin_amdgcn_global_load_lds((guint*)g, (luint*)l, 16, 0, 0);
}

__device__ __forceinline__ unsigned short f2bf_bits(float f) {
    union { float f; uint32_t u; } v; v.f = f;
    uint32_t u = v.u;
    return (unsigned short)((u + 0x7FFFu + ((u >> 16) & 1u)) >> 16);
}

// ---- convert x: f32 [4096][1024] -> bf16 same layout ----
__global__ void cvt_x_kernel(const float* __restrict__ x, unsigned short* __restrict__ xb) {
    const int i = (blockIdx.x * 256 + threadIdx.x) * 8;
    f32x4 a = *(const f32x4*)(x + i);
    f32x4 b = *(const f32x4*)(x + i + 4);
    short8 h;
#pragma unroll
    for (int e = 0; e < 4; ++e) { h[e] = (short)f2bf_bits(a[e]); h[e + 4] = (short)f2bf_bits(b[e]); }
    *(short8*)(xb + i) = h;
}

// ---- convert weight: f32 [m][n][j] -> bf16 [n][m][j] ----
__global__ void cvt_w_kernel(const float* __restrict__ w, unsigned short* __restrict__ wb) {
    const int mn = blockIdx.x;              // m*NCLS + n
    const int m = mn / NCLS, n = mn % NCLS;
    const float* src = w + (size_t)mn * FDIM;
    unsigned short* dst = wb + ((size_t)n * CDIM + m) * FDIM;
    const int c = threadIdx.x * 8;
    f32x4 a = *(const f32x4*)(src + c);
    f32x4 b = *(const f32x4*)(src + c + 4);
    short8 h;
#pragma unroll
    for (int e = 0; e < 4; ++e) { h[e] = (short)f2bf_bits(a[e]); h[e + 4] = (short)f2bf_bits(b[e]); }
    *(short8*)(dst + c) = h;
}

// ---- fused DUQ, 256x256x64, m201-exact dual-barrier 4-phase schedule ----
// Stage ledger (tile T staged during T-1): P0->A[0:128], P1->B[0:128],
// P2->B[128:256], P3->A[128:256]. Consumers: P0(T)={A0,B0}, P1={B1}, P2={A1}.
// Every load has 2-3 phases of latency cover. vmcnt(4) pre-closing-barrier at
// P0/P1/P3 retires exactly the half needed next; never drains to 0 mid-loop.
// Phase = { stage 2 gl_lds | phase ds_reads | [waits] | BAR | lgkm0 |
//           setprio(1) 16 MFMA setprio(0) | BAR }.
__global__ __launch_bounds__(512, 2)
void duq8(const unsigned short* __restrict__ xb, const unsigned short* __restrict__ wb,
          const float* __restrict__ csum, const float* __restrict__ cnum,
          float* __restrict__ out) {
    __shared__ unsigned short lsA[2][256 * 64];   // 2 x 32 KB
    __shared__ unsigned short lsB[2][256 * 64];   // 2 x 32 KB
    __shared__ float c_lds[CDIM];
    __shared__ float red[4][256];

    const int t    = threadIdx.x;
    const int bid  = blockIdx.x;
    const int n    = bid >> 4;       // class 0..99
    const int rt   = bid & 15;       // 256-row batch tile
    const int lane = t & 63;
    const int wm   = (t >> 6) >> 2;  // 0..1 : rows wm*128..+127
    const int wn   = (t >> 6) & 3;   // 0..3 : cols wn*64..+63
    const int ln15 = lane & 15;
    const int hi   = lane >> 4;

    {
        const float inv = 1.0f / cnum[n];
        for (int m = t; m < CDIM; m += 512)
            c_lds[m] = csum[(size_t)m * NCLS + n] * inv;
    }
    __syncthreads();

    // staging: thread covers row chunkbase+(t>>3), 16B at pre-swizzled col
    const int st_r = t >> 3;                       // 0..63
    const int st_c = ((t & 7) ^ (st_r & 7)) * 8;
    const unsigned short* gA = xb + ((size_t)(rt * 256 + st_r)) * FDIM + st_c;
    const unsigned short* gBb = wb + ((size_t)n * CDIM + st_r) * FDIM + st_c;
    const int ldst = st_r * 64 + (t & 7) * 8;      // linear dest (elements)

    auto stageA = [&](int rowoff, int tt, int bsel) {
        const int k_ = (tt & 15) * 64;
        gl_lds16(gA + (size_t)rowoff * FDIM + k_, &lsA[bsel][rowoff * 64 + ldst]);
    };
    auto stageB = [&](int rowoff, int tt, int bsel) {
        const int k_ = (tt & 15) * 64;
        const int pn_ = tt >> 4;
        gl_lds16(gBb + (size_t)(pn_ * 256 + rowoff) * FDIM + k_, &lsB[bsel][rowoff * 64 + ldst]);
    };

    f32x4 acc[8][4];
#pragma unroll
    for (int i = 0; i < 8; ++i)
#pragma unroll
        for (int j = 0; j < 4; ++j) acc[i][j] = f32x4{0.0f, 0.0f, 0.0f, 0.0f};

    // prologue: stage tile 0 in ledger order; retire halves sA0,sB0; barrier
    stageA(0, 0, 0);   stageA(64, 0, 0);     // sA0(0)
    stageB(0, 0, 0);   stageB(64, 0, 0);     // sB0(0)
    stageB(128, 0, 0); stageB(192, 0, 0);    // sB1(0)
    stageA(128, 0, 0); stageA(192, 0, 0);    // sA1(0)
    asm volatile("s_waitcnt vmcnt(4)" ::: "memory");
    __builtin_amdgcn_s_barrier();

    short8 a0[4][2], a1[4][2], b0[2][2], b1[2][2];

    for (int it = 0; it < 32; ++it) {
        const int bs  = it & 1;
        const int nbs = bs ^ 1;
        const bool more = (it + 1 < 32);
        const char* lA = (const char*)lsA[bs];
        const char* lB = (const char*)lsB[bs];

        // ================= P0 : Q(0,0)  reads A0(8)+B0(4) =================
        if (more) { stageA(0, it + 1, nbs); stageA(64, it + 1, nbs); }   // sA0(T+1)
#pragma unroll
        for (int i = 0; i < 4; ++i) {
            const int row = wm * 128 + i * 16 + ln15;
#pragma unroll
            for (int kk = 0; kk < 2; ++kk) {
                const int ba = (row * 128 + (kk * 32 + hi * 8) * 2) ^ ((row & 7) << 4);
                a0[i][kk] = *(const short8*)(lA + ba);
            }
        }
#pragma unroll
        for (int j = 0; j < 2; ++j) {
            const int row = wn * 64 + j * 16 + ln15;
#pragma unroll
            for (int kk = 0; kk < 2; ++kk) {
                const int bb = (row * 128 + (kk * 32 + hi * 8) * 2) ^ ((row & 7) << 4);
                b0[j][kk] = *(const short8*)(lB + bb);
            }
        }
        asm volatile("s_waitcnt lgkmcnt(8)" ::: "memory");        // pre-drain (12-read phase)
        if (more) asm volatile("s_waitcnt vmcnt(4)" ::: "memory"); // retire sB1(T)
        else      asm volatile("s_waitcnt vmcnt(2)" ::: "memory");
        __builtin_amdgcn_s_barrier();
        asm volatile("s_waitcnt lgkmcnt(0)" ::: "memory");
        __builtin_amdgcn_s_setprio(1);
#pragma unroll
        for (int i = 0; i < 4; ++i)
#pragma unroll
            for (int j = 0; j < 2; ++j)
#pragma unroll
                for (int kk = 0; kk < 2; ++kk)
                    acc[i][j] = __builtin_amdgcn_mfma_f32_16x16x32_bf16(
                        a0[i][kk], b0[j][kk], acc[i][j], 0, 0, 0);
        __builtin_amdgcn_s_setprio(0);
        asm volatile("" ::: "memory");
        __builtin_amdgcn_s_barrier();

        // ================= P1 : Q(0,1)  reads B1(4) =================
        if (more) { stageB(0, it + 1, nbs); stageB(64, it + 1, nbs); }   // sB0(T+1)
#pragma unroll
        for (int j = 0; j < 2; ++j) {
            const int row = wn * 64 + (2 + j) * 16 + ln15;
#pragma unroll
            for (int kk = 0; kk < 2; ++kk) {
                const int bb = (row * 128 + (kk * 32 + hi * 8) * 2) ^ ((row & 7) << 4);
                b1[j][kk] = *(const short8*)(lB + bb);
            }
        }
        if (more) asm volatile("s_waitcnt vmcnt(4)" ::: "memory"); // retire sA1(T)
        else      asm volatile("s_waitcnt vmcnt(0)" ::: "memory");
        __builtin_amdgcn_s_barrier();
        asm volatile("s_waitcnt lgkmcnt(0)" ::: "memory");
        __builtin_amdgcn_s_setprio(1);
#pragma unroll
        for (int i = 0; i < 4; ++i)
#pragma unroll
            for (int j = 0; j < 2; ++j)
#pragma unroll
                for (int kk = 0; kk < 2; ++kk)
                    acc[i][2 + j] = __builtin_amdgcn_mfma_f32_16x16x32_bf16(
                        a0[i][kk], b1[j][kk], acc[i][2 + j], 0, 0, 0);
        __builtin_amdgcn_s_setprio(0);
        asm volatile("" ::: "memory");
        __builtin_amdgcn_s_barrier();

        // ================= P2 : Q(1,1)  reads A1(8) =================
        if (more) { stageB(128, it + 1, nbs); stageB(192, it + 1, nbs); } // sB1(T+1)
#pragma unroll
        for (int i = 0; i < 4; ++i) {
            const int row = wm * 128 + 64 + i * 16 + ln15;
#pragma unroll
            for (int kk = 0; kk < 2; ++kk) {
                const int ba = (row * 128 + (kk * 32 + hi * 8) * 2) ^ ((row & 7) << 4);
                a1[i][kk] = *(const short8*)(lA + ba);
            }
        }
        asm volatile("" ::: "memory");
        __builtin_amdgcn_s_barrier();
        asm volatile("s_waitcnt lgkmcnt(0)" ::: "memory");
        __builtin_amdgcn_s_setprio(1);
#pragma unroll
        for (int i = 0; i < 4; ++i)
#pragma unroll
            for (int j = 0; j < 2; ++j)
#pragma unroll
                for (int kk = 0; kk < 2; ++kk)
                    acc[4 + i][2 + j] = __builtin_amdgcn_mfma_f32_16x16x32_bf16(
                        a1[i][kk], b1[j][kk], acc[4 + i][2 + j], 0, 0, 0);
        __builtin_amdgcn_s_setprio(0);
        asm volatile("" ::: "memory");
        __builtin_amdgcn_s_barrier();

        // ================= P3 : Q(1,0)  no reads =================
        if (more) { stageA(128, it + 1, nbs); stageA(192, it + 1, nbs); } // sA1(T+1)
        if (more) asm volatile("s_waitcnt vmcnt(4)" ::: "memory"); // retire sA0,sB0(T+1)
        asm volatile("" ::: "memory");
        __builtin_amdgcn_s_barrier();
        __builtin_amdgcn_s_setprio(1);
#pragma unroll
        for (int i = 0; i < 4; ++i)
#pragma unroll
            for (int j = 0; j < 2; ++j)
#pragma unroll
                for (int kk = 0; kk < 2; ++kk)
                    acc[4 + i][j] = __builtin_amdgcn_mfma_f32_16x16x32_bf16(
                        a1[i][kk], b0[j][kk], acc[4 + i][j], 0, 0, 0);
        __builtin_amdgcn_s_setprio(0);

        if ((it & 15) == 15) {       // panel epilogue: fold (z-c)^2
            const int pn = it >> 4;
            float p[8][4];
#pragma unroll
            for (int i = 0; i < 8; ++i)
#pragma unroll
                for (int r = 0; r < 4; ++r) p[i][r] = 0.0f;
#pragma unroll
            for (int i = 0; i < 8; ++i)
#pragma unroll
                for (int j = 0; j < 4; ++j) {
                    const int m = pn * 256 + wn * 64 + j * 16 + ln15;
                    const float c = c_lds[m];
#pragma unroll
                    for (int r = 0; r < 4; ++r) {
                        const float d = acc[i][j][r] - c;
                        p[i][r] += d * d;
                        acc[i][j][r] = 0.0f;
                    }
                }
#pragma unroll
            for (int i = 0; i < 8; ++i)
#pragma unroll
                for (int r = 0; r < 4; ++r) {
                    float v = p[i][r];
                    v += __shfl_xor(v, 1);
                    v += __shfl_xor(v, 2);
                    v += __shfl_xor(v, 4);
                    v += __shfl_xor(v, 8);
                    p[i][r] = v;
                }
            if (ln15 == 0) {
#pragma unroll
                for (int i = 0; i < 8; ++i)
#pragma unroll
                    for (int r = 0; r < 4; ++r) {
                        const int row = wm * 128 + i * 16 + hi * 4 + r;
                        if (pn == 0) red[wn][row] = p[i][r];
                        else         red[wn][row] += p[i][r];
                    }
            }
        }

        asm volatile("" ::: "memory");
        __builtin_amdgcn_s_barrier();
    }

    __syncthreads();
    if (t < 256) {
        const float sq = (red[0][t] + red[1][t] + red[2][t] + red[3][t]) * (1.0f / 512.0f);
        const float lc = -50.0f * sq;                    // -sq / (2*0.1^2)
        const size_t b = (size_t)rt * 256 + t;
        out[b * NCLS + n] = expf(lc);
        out[(size_t)NBATCH * NCLS + b * NCLS + n] = lc;
    }
}

// ---- fallback (no workspace): reg-staged inline-convert variant (r1, verified) ----
__global__ __launch_bounds__(256, 2)
void duq_fallback(const float* __restrict__ x, const float* __restrict__ w,
                  const float* __restrict__ csum, const float* __restrict__ cnum,
                  float* __restrict__ out) {
    __shared__ unsigned short lsA[128 * 64];
    __shared__ unsigned short lsB[128 * 64];
    __shared__ float c_lds[CDIM];
    __shared__ float red[2][128];

    const int t = threadIdx.x;
    const int n    = blockIdx.x >> 5;
    const int tile = blockIdx.x & 31;
    const int lane = t & 63;
    const int wid  = t >> 6;
    const int wrow = wid >> 1;
    const int wcol = wid & 1;
    const int ln15 = lane & 15;
    const int hi   = lane >> 4;

    {
        const float inv = 1.0f / cnum[n];
        for (int m = t; m < CDIM; m += 256)
            c_lds[m] = csum[(size_t)m * NCLS + n] * inv;
    }

    const int srow = t >> 3;
    const int scol = (t & 7) * 8;
    const int swz  = (srow & 7) << 4;

    float p[16];
#pragma unroll
    for (int q = 0; q < 16; ++q) p[q] = 0.0f;

    for (int chunk = 0; chunk < 4; ++chunk) {
        f32x4 acc[4][4];
#pragma unroll
        for (int i = 0; i < 4; ++i)
#pragma unroll
            for (int j = 0; j < 4; ++j)
                acc[i][j] = f32x4{0.0f, 0.0f, 0.0f, 0.0f};

        for (int ks = 0; ks < 16; ++ks) {
            const int k = ks * 64;
            __syncthreads();
#pragma unroll
            for (int pp = 0; pp < 4; ++pp) {
                const int row = pp * 32 + srow;
                const float* pa = x + ((size_t)(tile * 128 + row)) * FDIM + k + scol;
                const float* pb = w + ((size_t)(chunk * 128 + row) * NCLS + n) * FDIM + k + scol;
                f32x4 a0 = *(const f32x4*)pa, a1 = *(const f32x4*)(pa + 4);
                f32x4 b0 = *(const f32x4*)pb, b1 = *(const f32x4*)(pb + 4);
                short8 ha, hb;
#pragma unroll
                for (int e = 0; e < 4; ++e) {
                    ha[e] = (short)f2bf_bits(a0[e]); ha[e + 4] = (short)f2bf_bits(a1[e]);
                    hb[e] = (short)f2bf_bits(b0[e]); hb[e + 4] = (short)f2bf_bits(b1[e]);
                }
                const int byte = (row * 128 + scol * 2) ^ swz;
                *(short8*)((char*)lsA + byte) = ha;
                *(short8*)((char*)lsB + byte) = hb;
            }
            __syncthreads();
#pragma unroll
            for (int kk = 0; kk < 2; ++kk) {
                short8 afr[4], bfr[4];
#pragma unroll
                for (int i = 0; i < 4; ++i) {
                    const int rowA = wrow * 64 + i * 16 + ln15;
                    const int ba = (rowA * 128 + (kk * 32 + hi * 8) * 2) ^ ((rowA & 7) << 4);
                    afr[i] = *(const short8*)((const char*)lsA + ba);
                    const int rowB = wcol * 64 + i * 16 + ln15;
                    const int bb = (rowB * 128 + (kk * 32 + hi * 8) * 2) ^ ((rowB & 7) << 4);
                    bfr[i] = *(const short8*)((const char*)lsB + bb);
                }
#pragma unroll
                for (int i = 0; i < 4; ++i)
#pragma unroll
                    for (int j = 0; j < 4; ++j)
                        acc[i][j] = __builtin_amdgcn_mfma_f32_16x16x32_bf16(afr[i], bfr[j], acc[i][j], 0, 0, 0);
            }
        }

#pragma unroll
        for (int i = 0; i < 4; ++i)
#pragma unroll
            for (int j = 0; j < 4; ++j) {
                const int m = chunk * 128 + wcol * 64 + j * 16 + ln15;
                const float c = c_lds[m];
#pragma unroll
                for (int r = 0; r < 4; ++r) {
                    const float d = acc[i][j][r] - c;
                    p[i * 4 + r] += d * d;
                }
            }
    }

#pragma unroll
    for (int q = 0; q < 16; ++q) {
        float v = p[q];
        v += __shfl_xor(v, 1);
        v += __shfl_xor(v, 2);
        v += __shfl_xor(v, 4);
        v += __shfl_xor(v, 8);
        p[q] = v;
    }
    __syncthreads();
    if (ln15 == 0) {
#pragma unroll
        for (int i = 0; i < 4; ++i)
#pragma unroll
            for (int r = 0; r < 4; ++r)
                red[wcol][wrow * 64 + i * 16 + hi * 4 + r] = p[i * 4 + r];
    }
    __syncthreads();
    if (t < 128) {
        const float sq = (red[0][t] + red[1][t]) * (1.0f / 512.0f);
        const float lc = -50.0f * sq;
        const size_t b = (size_t)tile * 128 + t;
        out[b * NCLS + n] = expf(lc);
        out[(size_t)NBATCH * NCLS + b * NCLS + n] = lc;
    }
}

extern "C" void kernel_launch(void* const* d_in, const int* in_sizes, int n_in,
                              void* d_out, int out_size, void* d_ws, size_t ws_size,
                              hipStream_t stream) {
    const float* x    = (const float*)d_in[0];
    const float* w    = (const float*)d_in[1];
    const float* csum = (const float*)d_in[2];
    const float* cnum = (const float*)d_in[3];
    float* out = (float*)d_out;

    const size_t need = ((size_t)NBATCH * FDIM + (size_t)CDIM * NCLS * FDIM) * sizeof(unsigned short);

    if (ws_size >= need) {
        unsigned short* xb = (unsigned short*)d_ws;
        unsigned short* wb = xb + (size_t)NBATCH * FDIM;
        cvt_x_kernel<<<dim3((NBATCH * FDIM) / 2048), dim3(256), 0, stream>>>(x, xb);
        cvt_w_kernel<<<dim3(CDIM * NCLS), dim3(128), 0, stream>>>(w, wb);
        duq8<<<dim3(NCLS * 16), dim3(512), 0, stream>>>(xb, wb, csum, cnum, out);
    } else {
        duq_fallback<<<dim3(NCLS * 32), dim3(256), 0, stream>>>(x, w, csum, cnum, out);
    }
}

// Round 9
// 577.623 us; speedup vs baseline: 1.0558x; 1.0558x over previous
//
#include <hip/hip_runtime.h>
#include <hip/hip_bf16.h>
#include <stdint.h>

#define FDIM   1024
#define NCLS   100
#define CDIM   512
#define NBATCH 4096

typedef __attribute__((ext_vector_type(8)))  short short8;
typedef __attribute__((ext_vector_type(4)))  float f32x4;
typedef __attribute__((ext_vector_type(16))) float f32x16;

typedef const __attribute__((address_space(1))) unsigned int guint;
typedef __attribute__((address_space(3))) unsigned int luint;

__device__ __forceinline__ void gl_lds16(const unsigned short* g, unsigned short* l) {
    __builtin_amdgcn_global_load_lds((guint*)g, (luint*)l, 16, 0, 0);
}

__device__ __forceinline__ unsigned short f2bf_bits(float f) {
    union { float f; uint32_t u; } v; v.f = f;
    uint32_t u = v.u;
    return (unsigned short)((u + 0x7FFFu + ((u >> 16) & 1u)) >> 16);
}

// ---- convert x: f32 [4096][1024] -> bf16 same layout ----
__global__ void cvt_x_kernel(const float* __restrict__ x, unsigned short* __restrict__ xb) {
    const int i = (blockIdx.x * 256 + threadIdx.x) * 8;
    f32x4 a = *(const f32x4*)(x + i);
    f32x4 b = *(const f32x4*)(x + i + 4);
    short8 h;
#pragma unroll
    for (int e = 0; e < 4; ++e) { h[e] = (short)f2bf_bits(a[e]); h[e + 4] = (short)f2bf_bits(b[e]); }
    *(short8*)(xb + i) = h;
}

// ---- convert weight: f32 [m][n][j] -> bf16 [n][m][j] ----
__global__ void cvt_w_kernel(const float* __restrict__ w, unsigned short* __restrict__ wb) {
    const int mn = blockIdx.x;              // m*NCLS + n
    const int m = mn / NCLS, n = mn % NCLS;
    const float* src = w + (size_t)mn * FDIM;
    unsigned short* dst = wb + ((size_t)n * CDIM + m) * FDIM;
    const int c = threadIdx.x * 8;
    f32x4 a = *(const f32x4*)(src + c);
    f32x4 b = *(const f32x4*)(src + c + 4);
    short8 h;
#pragma unroll
    for (int e = 0; e < 4; ++e) { h[e] = (short)f2bf_bits(a[e]); h[e + 4] = (short)f2bf_bits(b[e]); }
    *(short8*)(dst + c) = h;
}

// ---- fused DUQ GEMM block: 256 batch x 256 m-cols (one class, one m-half) ----
// 3200 blocks (12.5/CU, ~4% tail). 32x32x16 MFMA (-17% matrix cycles).
// r3-proven single-barrier K-loop (16 iters). Cross-wn reduction via red[] LDS
// (r8 bug: waves raced on sqp); one partial per mh half -> finisher sums 2.
__global__ __launch_bounds__(512, 2)
void duq32(const unsigned short* __restrict__ xb, const unsigned short* __restrict__ wb,
           const float* __restrict__ csum, const float* __restrict__ cnum,
           float* __restrict__ sqp) {
    __shared__ unsigned short lsA[2][256 * 64];   // 2 x 32 KB
    __shared__ unsigned short lsB[2][256 * 64];   // 2 x 32 KB
    __shared__ float c_lds[256];
    __shared__ float red[4][256];

    const int t    = threadIdx.x;
    const int bid  = blockIdx.x;           // n*32 + rt*2 + mh
    const int n    = bid >> 5;             // class 0..99
    const int rt   = (bid >> 1) & 15;      // 256-row batch tile
    const int mh   = bid & 1;              // m half: [mh*256, +256)
    const int lane = t & 63;
    const int wm   = (t >> 6) >> 2;        // 0..1 : batch rows wm*128..+127
    const int wn   = (t >> 6) & 3;         // 0..3 : m cols wn*64..+63
    const int l31  = lane & 31;
    const int h5   = lane >> 5;            // 0..1

    {   // centroids for this block's 256 m's
        const float inv = 1.0f / cnum[n];
        for (int i = t; i < 256; i += 512)
            c_lds[i] = csum[(size_t)(mh * 256 + i) * NCLS + n] * inv;
    }

    // staging: thread t covers row chunkbase+(t>>3), 16B at pre-swizzled col
    const int st_r = t >> 3;                       // 0..63
    const int st_c = ((t & 7) ^ (st_r & 7)) * 8;
    const unsigned short* gA = xb + ((size_t)(rt * 256 + st_r)) * FDIM + st_c;
    const unsigned short* gB = wb + ((size_t)(n * CDIM + mh * 256 + st_r)) * FDIM + st_c;
    const int ldst = st_r * 64 + (t & 7) * 8;      // linear dest (elements)

    auto stage = [&](int it_, int bsel_) {
        const int k_ = it_ * 64;
#pragma unroll
        for (int c = 0; c < 4; ++c) {
            gl_lds16(gA + (size_t)(c * 64) * FDIM + k_, &lsA[bsel_][c * 4096 + ldst]);
            gl_lds16(gB + (size_t)(c * 64) * FDIM + k_, &lsB[bsel_][c * 4096 + ldst]);
        }
    };

    f32x16 acc[4][2];
#pragma unroll
    for (int i = 0; i < 4; ++i)
#pragma unroll
        for (int j = 0; j < 2; ++j)
#pragma unroll
            for (int r = 0; r < 16; ++r) acc[i][j][r] = 0.0f;

    stage(0, 0);
    __syncthreads();     // drains gl_lds; also publishes c_lds

    short8 afr[2][4], bfr[2][2];

#define LOADK(KS, SLOT)                                                          \
    {                                                                            \
        _Pragma("unroll")                                                        \
        for (int fi = 0; fi < 4; ++fi) {                                         \
            const int row = wm * 128 + fi * 32 + l31;                            \
            const int ba = (row * 128 + (KS) * 32 + h5 * 16) ^ ((row & 7) << 4); \
            afr[SLOT][fi] = *(const short8*)(lA + ba);                           \
        }                                                                        \
        _Pragma("unroll")                                                        \
        for (int fj = 0; fj < 2; ++fj) {                                         \
            const int row = wn * 64 + fj * 32 + l31;                             \
            const int bb = (row * 128 + (KS) * 32 + h5 * 16) ^ ((row & 7) << 4); \
            bfr[SLOT][fj] = *(const short8*)(lB + bb);                           \
        }                                                                        \
    }

    for (int it = 0; it < 16; ++it) {
        const int bs = it & 1;
        if (it + 1 < 16) stage(it + 1, bs ^ 1);   // safe: readers of bs^1 passed last barrier
        const char* lA = (const char*)lsA[bs];
        const char* lB = (const char*)lsB[bs];

        LOADK(0, 0);
#pragma unroll
        for (int ks = 0; ks < 4; ++ks) {
            const int cur = ks & 1;
            if (ks == 0)      LOADK(1, 1)
            else if (ks == 1) LOADK(2, 0)
            else if (ks == 2) LOADK(3, 1)
            __builtin_amdgcn_s_setprio(1);
#pragma unroll
            for (int fi = 0; fi < 4; ++fi)
#pragma unroll
                for (int fj = 0; fj < 2; ++fj)
                    acc[fi][fj] = __builtin_amdgcn_mfma_f32_32x32x16_bf16(
                        afr[cur][fi], bfr[cur][fj], acc[fi][fj], 0, 0, 0);
            __builtin_amdgcn_s_setprio(0);
        }
        __syncthreads();   // drains vmcnt (stage it+1, full compute cover) + readers done
    }
#undef LOADK

    // epilogue: (z-c)^2 partial over this wave's 64 m-cols, reduce, stash in red
    const float c0 = c_lds[wn * 64 + l31];
    const float c1 = c_lds[wn * 64 + 32 + l31];
#pragma unroll
    for (int fi = 0; fi < 4; ++fi) {
        float p[16];
#pragma unroll
        for (int r = 0; r < 16; ++r) {
            const float d0 = acc[fi][0][r] - c0;
            const float d1 = acc[fi][1][r] - c1;
            p[r] = d0 * d0 + d1 * d1;
        }
#pragma unroll
        for (int r = 0; r < 16; ++r) {       // sum over 32 m-cols (lanes within half)
            float v = p[r];
            v += __shfl_xor(v, 1);
            v += __shfl_xor(v, 2);
            v += __shfl_xor(v, 4);
            v += __shfl_xor(v, 8);
            v += __shfl_xor(v, 16);
            p[r] = v;
        }
        // C/D row = (r&3)+8*(r>>2)+4*h5 (m74/m101); static-index predicated write
#pragma unroll
        for (int r = 0; r < 16; ++r) {
            if (l31 == r)
                red[wn][wm * 128 + fi * 32 + (r & 3) + 8 * (r >> 2) + 4 * h5] = p[r];
        }
    }
    __syncthreads();
    if (t < 256) {       // sum the 4 wn partials -> one value per batch row
        const float s = red[0][t] + red[1][t] + red[2][t] + red[3][t];
        sqp[(size_t)mh * (NBATCH * NCLS) + (size_t)(rt * 256 + t) * NCLS + n] = s;
    }
}

// ---- finisher: sum 2 m-half partials, scale, exp ----
__global__ void finish_kernel(const float* __restrict__ sqp, float* __restrict__ out) {
    const int i = blockIdx.x * 256 + threadIdx.x;   // 0..409599
    const float v  = sqp[i] + sqp[NBATCH * NCLS + i];
    const float lc = v * (-50.0f / 512.0f);         // -(v/512)/(2*0.1^2)
    out[i] = expf(lc);
    out[NBATCH * NCLS + i] = lc;
}

// ---- fallback (no workspace): reg-staged inline-convert variant (r1, verified) ----
__global__ __launch_bounds__(256, 2)
void duq_fallback(const float* __restrict__ x, const float* __restrict__ w,
                  const float* __restrict__ csum, const float* __restrict__ cnum,
                  float* __restrict__ out) {
    __shared__ unsigned short lsA[128 * 64];
    __shared__ unsigned short lsB[128 * 64];
    __shared__ float c_lds[CDIM];
    __shared__ float red[2][128];

    const int t = threadIdx.x;
    const int n    = blockIdx.x >> 5;
    const int tile = blockIdx.x & 31;
    const int lane = t & 63;
    const int wid  = t >> 6;
    const int wrow = wid >> 1;
    const int wcol = wid & 1;
    const int ln15 = lane & 15;
    const int hi   = lane >> 4;

    {
        const float inv = 1.0f / cnum[n];
        for (int m = t; m < CDIM; m += 256)
            c_lds[m] = csum[(size_t)m * NCLS + n] * inv;
    }

    const int srow = t >> 3;
    const int scol = (t & 7) * 8;
    const int swz  = (srow & 7) << 4;

    float p[16];
#pragma unroll
    for (int q = 0; q < 16; ++q) p[q] = 0.0f;

    for (int chunk = 0; chunk < 4; ++chunk) {
        f32x4 acc[4][4];
#pragma unroll
        for (int i = 0; i < 4; ++i)
#pragma unroll
            for (int j = 0; j < 4; ++j)
                acc[i][j] = f32x4{0.0f, 0.0f, 0.0f, 0.0f};

        for (int ks = 0; ks < 16; ++ks) {
            const int k = ks * 64;
            __syncthreads();
#pragma unroll
            for (int pp = 0; pp < 4; ++pp) {
                const int row = pp * 32 + srow;
                const float* pa = x + ((size_t)(tile * 128 + row)) * FDIM + k + scol;
                const float* pb = w + ((size_t)(chunk * 128 + row) * NCLS + n) * FDIM + k + scol;
                f32x4 a0 = *(const f32x4*)pa, a1 = *(const f32x4*)(pa + 4);
                f32x4 b0 = *(const f32x4*)pb, b1 = *(const f32x4*)(pb + 4);
                short8 ha, hb;
#pragma unroll
                for (int e = 0; e < 4; ++e) {
                    ha[e] = (short)f2bf_bits(a0[e]); ha[e + 4] = (short)f2bf_bits(a1[e]);
                    hb[e] = (short)f2bf_bits(b0[e]); hb[e + 4] = (short)f2bf_bits(b1[e]);
                }
                const int byte = (row * 128 + scol * 2) ^ swz;
                *(short8*)((char*)lsA + byte) = ha;
                *(short8*)((char*)lsB + byte) = hb;
            }
            __syncthreads();
#pragma unroll
            for (int kk = 0; kk < 2; ++kk) {
                short8 afr[4], bfr[4];
#pragma unroll
                for (int i = 0; i < 4; ++i) {
                    const int rowA = wrow * 64 + i * 16 + ln15;
                    const int ba = (rowA * 128 + (kk * 32 + hi * 8) * 2) ^ ((rowA & 7) << 4);
                    afr[i] = *(const short8*)((const char*)lsA + ba);
                    const int rowB = wcol * 64 + i * 16 + ln15;
                    const int bb = (rowB * 128 + (kk * 32 + hi * 8) * 2) ^ ((rowB & 7) << 4);
                    bfr[i] = *(const short8*)((const char*)lsB + bb);
                }
#pragma unroll
                for (int i = 0; i < 4; ++i)
#pragma unroll
                    for (int j = 0; j < 4; ++j)
                        acc[i][j] = __builtin_amdgcn_mfma_f32_16x16x32_bf16(afr[i], bfr[j], acc[i][j], 0, 0, 0);
            }
        }

#pragma unroll
        for (int i = 0; i < 4; ++i)
#pragma unroll
            for (int j = 0; j < 4; ++j) {
                const int m = chunk * 128 + wcol * 64 + j * 16 + ln15;
                const float c = c_lds[m];
#pragma unroll
                for (int r = 0; r < 4; ++r) {
                    const float d = acc[i][j][r] - c;
                    p[i * 4 + r] += d * d;
                }
            }
    }

#pragma unroll
    for (int q = 0; q < 16; ++q) {
        float v = p[q];
        v += __shfl_xor(v, 1);
        v += __shfl_xor(v, 2);
        v += __shfl_xor(v, 4);
        v += __shfl_xor(v, 8);
        p[q] = v;
    }
    __syncthreads();
    if (ln15 == 0) {
#pragma unroll
        for (int i = 0; i < 4; ++i)
#pragma unroll
            for (int r = 0; r < 4; ++r)
                red[wcol][wrow * 64 + i * 16 + hi * 4 + r] = p[i * 4 + r];
    }
    __syncthreads();
    if (t < 128) {
        const float sq = (red[0][t] + red[1][t]) * (1.0f / 512.0f);
        const float lc = -50.0f * sq;
        const size_t b = (size_t)tile * 128 + t;
        out[b * NCLS + n] = expf(lc);
        out[(size_t)NBATCH * NCLS + b * NCLS + n] = lc;
    }
}

extern "C" void kernel_launch(void* const* d_in, const int* in_sizes, int n_in,
                              void* d_out, int out_size, void* d_ws, size_t ws_size,
                              hipStream_t stream) {
    const float* x    = (const float*)d_in[0];
    const float* w    = (const float*)d_in[1];
    const float* csum = (const float*)d_in[2];
    const float* cnum = (const float*)d_in[3];
    float* out = (float*)d_out;

    const size_t nxb = (size_t)NBATCH * FDIM;          // 4.19M bf16
    const size_t nwb = (size_t)CDIM * NCLS * FDIM;     // 52.4M bf16
    const size_t need = (nxb + nwb) * sizeof(unsigned short)
                      + (size_t)2 * NBATCH * NCLS * sizeof(float);

    if (ws_size >= need) {
        unsigned short* xb = (unsigned short*)d_ws;
        unsigned short* wb = xb + nxb;
        float* sqp = (float*)(wb + nwb);
        cvt_x_kernel<<<dim3((NBATCH * FDIM) / 2048), dim3(256), 0, stream>>>(x, xb);
        cvt_w_kernel<<<dim3(CDIM * NCLS), dim3(128), 0, stream>>>(w, wb);
        duq32<<<dim3(NCLS * 32), dim3(512), 0, stream>>>(xb, wb, csum, cnum, sqp);
        finish_kernel<<<dim3((NBATCH * NCLS) / 256), dim3(256), 0, stream>>>(sqp, out);
    } else {
        duq_fallback<<<dim3(NCLS * 32), dim3(256), 0, stream>>>(x, w, csum, cnum, out);
    }
}

// Round 10
// 489.856 us; speedup vs baseline: 1.2450x; 1.1792x over previous
//
#include <hip/hip_runtime.h>
#include <hip/hip_bf16.h>
#include <stdint.h>

#define FDIM   1024
#define NCLS   100
#define CDIM   512
#define NBATCH 4096

typedef __attribute__((ext_vector_type(8))) short short8;
typedef __attribute__((ext_vector_type(4))) float f32x4;

typedef const __attribute__((address_space(1))) unsigned int guint;
typedef __attribute__((address_space(3))) unsigned int luint;

__device__ __forceinline__ void gl_lds16(const unsigned short* g, unsigned short* l) {
    __builtin_amdgcn_global_load_lds((guint*)g, (luint*)l, 16, 0, 0);
}

__device__ __forceinline__ unsigned short f2bf_bits(float f) {
    union { float f; uint32_t u; } v; v.f = f;
    uint32_t u = v.u;
    return (unsigned short)((u + 0x7FFFu + ((u >> 16) & 1u)) >> 16);
}

// ---- convert x: f32 [4096][1024] -> bf16 same layout ----
__global__ void cvt_x_kernel(const float* __restrict__ x, unsigned short* __restrict__ xb) {
    const int i = (blockIdx.x * 256 + threadIdx.x) * 8;
    f32x4 a = *(const f32x4*)(x + i);
    f32x4 b = *(const f32x4*)(x + i + 4);
    short8 h;
#pragma unroll
    for (int e = 0; e < 4; ++e) { h[e] = (short)f2bf_bits(a[e]); h[e + 4] = (short)f2bf_bits(b[e]); }
    *(short8*)(xb + i) = h;
}

// ---- convert weight: f32 [m][n][j] -> bf16 [n][m][j] ----
__global__ void cvt_w_kernel(const float* __restrict__ w, unsigned short* __restrict__ wb) {
    const int mn = blockIdx.x;              // m*NCLS + n
    const int m = mn / NCLS, n = mn % NCLS;
    const float* src = w + (size_t)mn * FDIM;
    unsigned short* dst = wb + ((size_t)n * CDIM + m) * FDIM;
    const int c = threadIdx.x * 8;
    f32x4 a = *(const f32x4*)(src + c);
    f32x4 b = *(const f32x4*)(src + c + 4);
    short8 h;
#pragma unroll
    for (int e = 0; e < 4; ++e) { h[e] = (short)f2bf_bits(a[e]); h[e + 4] = (short)f2bf_bits(b[e]); }
    *(short8*)(dst + c) = h;
}

// ---- fused DUQ GEMM block: 256 batch x 256 m-cols (one class, one m-half) ----
// r3-proven burst single-barrier K-loop + 16x16x32 MFMA (verified 0-conflict
// LOADK pattern) + 3200-block grid (0.96 tail eff vs 0.89) + sqp/finisher.
__global__ __launch_bounds__(512, 2)
void duq16(const unsigned short* __restrict__ xb, const unsigned short* __restrict__ wb,
           const float* __restrict__ csum, const float* __restrict__ cnum,
           float* __restrict__ sqp) {
    __shared__ unsigned short lsA[2][256 * 64];   // 2 x 32 KB
    __shared__ unsigned short lsB[2][256 * 64];   // 2 x 32 KB
    __shared__ float c_lds[256];
    __shared__ float red[4][256];

    const int t    = threadIdx.x;
    const int bid  = blockIdx.x;           // n*32 + rt*2 + mh (32 consecutive share class weights)
    const int n    = bid >> 5;             // class 0..99
    const int rt   = (bid >> 1) & 15;      // 256-row batch tile
    const int mh   = bid & 1;              // m half: [mh*256, +256)
    const int lane = t & 63;
    const int wid  = t >> 6;               // 0..7
    const int wm   = wid >> 2;             // 0..1 : batch rows wm*128..+127
    const int wn   = wid & 3;              // 0..3 : m cols wn*64..+63
    const int ln15 = lane & 15;
    const int hi   = lane >> 4;            // 0..3

    {   // centroids for this block's 256 m's
        const float inv = 1.0f / cnum[n];
        for (int i = t; i < 256; i += 512)
            c_lds[i] = csum[(size_t)(mh * 256 + i) * NCLS + n] * inv;
    }

    // staging: thread t covers row chunkbase+(t>>3), 16B at pre-swizzled col
    const int st_r = t >> 3;                       // 0..63
    const int st_c = ((t & 7) ^ (st_r & 7)) * 8;
    const unsigned short* gA = xb + ((size_t)(rt * 256 + st_r)) * FDIM + st_c;
    const unsigned short* gB = wb + ((size_t)(n * CDIM + mh * 256 + st_r)) * FDIM + st_c;

    auto stage = [&](int it_, int bsel_) {
        const int k_ = it_ * 64;
#pragma unroll
        for (int c = 0; c < 4; ++c) {
            gl_lds16(gA + (size_t)(c * 64) * FDIM + k_, &lsA[bsel_][c * 4096 + wid * 512]);
            gl_lds16(gB + (size_t)(c * 64) * FDIM + k_, &lsB[bsel_][c * 4096 + wid * 512]);
        }
    };

    f32x4 acc[8][4];
#pragma unroll
    for (int i = 0; i < 8; ++i)
#pragma unroll
        for (int j = 0; j < 4; ++j) acc[i][j] = f32x4{0.0f, 0.0f, 0.0f, 0.0f};

    stage(0, 0);
    __syncthreads();                 // drains this wave's gl_lds; barrier => tile 0 complete

    for (int it = 0; it < 16; ++it) {
        const int bs = it & 1;
        if (it + 1 < 16) stage(it + 1, bs ^ 1);   // other buffer: prev readers passed last barrier

        short8 af[2][4][2];          // [qr][i][kk], loaded at qc==0
        short8 bf[2][2][2];          // [qc][j][kk], loaded at qr==0
#pragma unroll
        for (int qr = 0; qr < 2; ++qr) {
#pragma unroll
            for (int qc = 0; qc < 2; ++qc) {
                if (qc == 0) {
#pragma unroll
                    for (int i = 0; i < 4; ++i) {
                        const int rowA = wm * 128 + (qr * 4 + i) * 16 + ln15;
#pragma unroll
                        for (int kk = 0; kk < 2; ++kk) {
                            const int ba = (rowA * 128 + (kk * 32 + hi * 8) * 2) ^ ((rowA & 7) << 4);
                            af[qr][i][kk] = *(const short8*)((const char*)lsA[bs] + ba);
                        }
                    }
                }
                if (qr == 0) {
#pragma unroll
                    for (int j = 0; j < 2; ++j) {
                        const int rowB = wn * 64 + (qc * 2 + j) * 16 + ln15;
#pragma unroll
                        for (int kk = 0; kk < 2; ++kk) {
                            const int bb = (rowB * 128 + (kk * 32 + hi * 8) * 2) ^ ((rowB & 7) << 4);
                            bf[qc][j][kk] = *(const short8*)((const char*)lsB[bs] + bb);
                        }
                    }
                }
                __builtin_amdgcn_s_setprio(1);
#pragma unroll
                for (int i = 0; i < 4; ++i)
#pragma unroll
                    for (int j = 0; j < 2; ++j)
#pragma unroll
                        for (int kk = 0; kk < 2; ++kk)
                            acc[qr * 4 + i][qc * 2 + j] =
                                __builtin_amdgcn_mfma_f32_16x16x32_bf16(
                                    af[qr][i][kk], bf[qc][j][kk],
                                    acc[qr * 4 + i][qc * 2 + j], 0, 0, 0);
                __builtin_amdgcn_s_setprio(0);
            }
        }
        __syncthreads();             // per-wave vmcnt drain (covered) + readers done with buf bs
    }

    // epilogue: (z-c)^2 over this wave's 64 m-cols, reduce 16 lanes, stash red
    float p[8][4];
#pragma unroll
    for (int i = 0; i < 8; ++i)
#pragma unroll
        for (int r = 0; r < 4; ++r) p[i][r] = 0.0f;
#pragma unroll
    for (int i = 0; i < 8; ++i)
#pragma unroll
        for (int j = 0; j < 4; ++j) {
            const float c = c_lds[wn * 64 + j * 16 + ln15];
#pragma unroll
            for (int r = 0; r < 4; ++r) {
                const float d = acc[i][j][r] - c;
                p[i][r] += d * d;
            }
        }
#pragma unroll
    for (int i = 0; i < 8; ++i)
#pragma unroll
        for (int r = 0; r < 4; ++r) {
            float v = p[i][r];
            v += __shfl_xor(v, 1);
            v += __shfl_xor(v, 2);
            v += __shfl_xor(v, 4);
            v += __shfl_xor(v, 8);
            p[i][r] = v;
        }
    if (ln15 == 0) {
#pragma unroll
        for (int i = 0; i < 8; ++i)
#pragma unroll
            for (int r = 0; r < 4; ++r)
                red[wn][wm * 128 + i * 16 + hi * 4 + r] = p[i][r];
    }
    __syncthreads();
    if (t < 256) {       // sum the 4 wn partials -> one value per batch row
        const float s = red[0][t] + red[1][t] + red[2][t] + red[3][t];
        sqp[(size_t)mh * (NBATCH * NCLS) + (size_t)(rt * 256 + t) * NCLS + n] = s;
    }
}

// ---- finisher: sum 2 m-half partials, scale, exp ----
__global__ void finish_kernel(const float* __restrict__ sqp, float* __restrict__ out) {
    const int i = blockIdx.x * 256 + threadIdx.x;   // 0..409599
    const float v  = sqp[i] + sqp[NBATCH * NCLS + i];
    const float lc = v * (-50.0f / 512.0f);         // -(v/512)/(2*0.1^2)
    out[i] = expf(lc);
    out[NBATCH * NCLS + i] = lc;
}

// ---- fallback (no workspace): reg-staged inline-convert variant (r1, verified) ----
__global__ __launch_bounds__(256, 2)
void duq_fallback(const float* __restrict__ x, const float* __restrict__ w,
                  const float* __restrict__ csum, const float* __restrict__ cnum,
                  float* __restrict__ out) {
    __shared__ unsigned short lsA[128 * 64];
    __shared__ unsigned short lsB[128 * 64];
    __shared__ float c_lds[CDIM];
    __shared__ float red[2][128];

    const int t = threadIdx.x;
    const int n    = blockIdx.x >> 5;
    const int tile = blockIdx.x & 31;
    const int lane = t & 63;
    const int wid  = t >> 6;
    const int wrow = wid >> 1;
    const int wcol = wid & 1;
    const int ln15 = lane & 15;
    const int hi   = lane >> 4;

    {
        const float inv = 1.0f / cnum[n];
        for (int m = t; m < CDIM; m += 256)
            c_lds[m] = csum[(size_t)m * NCLS + n] * inv;
    }

    const int srow = t >> 3;
    const int scol = (t & 7) * 8;
    const int swz  = (srow & 7) << 4;

    float p[16];
#pragma unroll
    for (int q = 0; q < 16; ++q) p[q] = 0.0f;

    for (int chunk = 0; chunk < 4; ++chunk) {
        f32x4 acc[4][4];
#pragma unroll
        for (int i = 0; i < 4; ++i)
#pragma unroll
            for (int j = 0; j < 4; ++j)
                acc[i][j] = f32x4{0.0f, 0.0f, 0.0f, 0.0f};

        for (int ks = 0; ks < 16; ++ks) {
            const int k = ks * 64;
            __syncthreads();
#pragma unroll
            for (int pp = 0; pp < 4; ++pp) {
                const int row = pp * 32 + srow;
                const float* pa = x + ((size_t)(tile * 128 + row)) * FDIM + k + scol;
                const float* pb = w + ((size_t)(chunk * 128 + row) * NCLS + n) * FDIM + k + scol;
                f32x4 a0 = *(const f32x4*)pa, a1 = *(const f32x4*)(pa + 4);
                f32x4 b0 = *(const f32x4*)pb, b1 = *(const f32x4*)(pb + 4);
                short8 ha, hb;
#pragma unroll
                for (int e = 0; e < 4; ++e) {
                    ha[e] = (short)f2bf_bits(a0[e]); ha[e + 4] = (short)f2bf_bits(a1[e]);
                    hb[e] = (short)f2bf_bits(b0[e]); hb[e + 4] = (short)f2bf_bits(b1[e]);
                }
                const int byte = (row * 128 + scol * 2) ^ swz;
                *(short8*)((char*)lsA + byte) = ha;
                *(short8*)((char*)lsB + byte) = hb;
            }
            __syncthreads();
#pragma unroll
            for (int kk = 0; kk < 2; ++kk) {
                short8 afr[4], bfr[4];
#pragma unroll
                for (int i = 0; i < 4; ++i) {
                    const int rowA = wrow * 64 + i * 16 + ln15;
                    const int ba = (rowA * 128 + (kk * 32 + hi * 8) * 2) ^ ((rowA & 7) << 4);
                    afr[i] = *(const short8*)((const char*)lsA + ba);
                    const int rowB = wcol * 64 + i * 16 + ln15;
                    const int bb = (rowB * 128 + (kk * 32 + hi * 8) * 2) ^ ((rowB & 7) << 4);
                    bfr[i] = *(const short8*)((const char*)lsB + bb);
                }
#pragma unroll
                for (int i = 0; i < 4; ++i)
#pragma unroll
                    for (int j = 0; j < 4; ++j)
                        acc[i][j] = __builtin_amdgcn_mfma_f32_16x16x32_bf16(afr[i], bfr[j], acc[i][j], 0, 0, 0);
            }
        }

#pragma unroll
        for (int i = 0; i < 4; ++i)
#pragma unroll
            for (int j = 0; j < 4; ++j) {
                const int m = chunk * 128 + wcol * 64 + j * 16 + ln15;
                const float c = c_lds[m];
#pragma unroll
                for (int r = 0; r < 4; ++r) {
                    const float d = acc[i][j][r] - c;
                    p[i * 4 + r] += d * d;
                }
            }
    }

#pragma unroll
    for (int q = 0; q < 16; ++q) {
        float v = p[q];
        v += __shfl_xor(v, 1);
        v += __shfl_xor(v, 2);
        v += __shfl_xor(v, 4);
        v += __shfl_xor(v, 8);
        p[q] = v;
    }
    __syncthreads();
    if (ln15 == 0) {
#pragma unroll
        for (int i = 0; i < 4; ++i)
#pragma unroll
            for (int r = 0; r < 4; ++r)
                red[wcol][wrow * 64 + i * 16 + hi * 4 + r] = p[i * 4 + r];
    }
    __syncthreads();
    if (t < 128) {
        const float sq = (red[0][t] + red[1][t]) * (1.0f / 512.0f);
        const float lc = -50.0f * sq;
        const size_t b = (size_t)tile * 128 + t;
        out[b * NCLS + n] = expf(lc);
        out[(size_t)NBATCH * NCLS + b * NCLS + n] = lc;
    }
}

extern "C" void kernel_launch(void* const* d_in, const int* in_sizes, int n_in,
                              void* d_out, int out_size, void* d_ws, size_t ws_size,
                              hipStream_t stream) {
    const float* x    = (const float*)d_in[0];
    const float* w    = (const float*)d_in[1];
    const float* csum = (const float*)d_in[2];
    const float* cnum = (const float*)d_in[3];
    float* out = (float*)d_out;

    const size_t nxb = (size_t)NBATCH * FDIM;          // 4.19M bf16
    const size_t nwb = (size_t)CDIM * NCLS * FDIM;     // 52.4M bf16
    const size_t need = (nxb + nwb) * sizeof(unsigned short)
                      + (size_t)2 * NBATCH * NCLS * sizeof(float);

    if (ws_size >= need) {
        unsigned short* xb = (unsigned short*)d_ws;
        unsigned short* wb = xb + nxb;
        float* sqp = (float*)(wb + nwb);
        cvt_x_kernel<<<dim3((NBATCH * FDIM) / 2048), dim3(256), 0, stream>>>(x, xb);
        cvt_w_kernel<<<dim3(CDIM * NCLS), dim3(128), 0, stream>>>(w, wb);
        duq16<<<dim3(NCLS * 32), dim3(512), 0, stream>>>(xb, wb, csum, cnum, sqp);
        finish_kernel<<<dim3((NBATCH * NCLS) / 256), dim3(256), 0, stream>>>(sqp, out);
    } else {
        duq_fallback<<<dim3(NCLS * 32), dim3(256), 0, stream>>>(x, w, csum, cnum, out);
    }
}

// Round 11
// 275.334 us; speedup vs baseline: 2.2150x; 1.7791x over previous
//
#include <hip/hip_runtime.h>
#include <hip/hip_bf16.h>
#include <stdint.h>

#define FDIM   1024
#define NCLS   100
#define CDIM   512
#define NBATCH 4096

typedef __attribute__((ext_vector_type(8))) short short8;
typedef __attribute__((ext_vector_type(4))) float f32x4;
typedef __attribute__((ext_vector_type(4))) int  int4v;
typedef __attribute__((ext_vector_type(8))) int  int8v;
typedef __attribute__((ext_vector_type(2))) int  int2v;

typedef const __attribute__((address_space(1))) unsigned int guint;
typedef __attribute__((address_space(3))) unsigned int luint;

__device__ __forceinline__ void gl_lds16b(const uint8_t* g, uint8_t* l) {
    __builtin_amdgcn_global_load_lds((guint*)g, (luint*)l, 16, 0, 0);
}

__device__ __forceinline__ unsigned short f2bf_bits(float f) {
    union { float f; uint32_t u; } v; v.f = f;
    uint32_t u = v.u;
    return (unsigned short)((u + 0x7FFFu + ((u >> 16) & 1u)) >> 16);
}

// ---- convert x: f32 [4096][1024] -> fp8 e4m3 (OCP, HW RNE) same layout ----
__global__ void cvt_x8(const float* __restrict__ x, uint8_t* __restrict__ xq) {
    const int i = (blockIdx.x * 256 + threadIdx.x) * 8;
    f32x4 a = *(const f32x4*)(x + i);
    f32x4 b = *(const f32x4*)(x + i + 4);
    int lo = 0, hi = 0;
    lo = __builtin_amdgcn_cvt_pk_fp8_f32(a[0], a[1], lo, false);
    lo = __builtin_amdgcn_cvt_pk_fp8_f32(a[2], a[3], lo, true);
    hi = __builtin_amdgcn_cvt_pk_fp8_f32(b[0], b[1], hi, false);
    hi = __builtin_amdgcn_cvt_pk_fp8_f32(b[2], b[3], hi, true);
    int2v v; v[0] = lo; v[1] = hi;
    *(int2v*)(xq + i) = v;
}

// ---- convert weight: f32 [m][n][j] -> fp8 [n][m][j] ----
__global__ void cvt_w8(const float* __restrict__ w, uint8_t* __restrict__ wq) {
    const int mn = blockIdx.x;              // m*NCLS + n
    const int m = mn / NCLS, n = mn % NCLS;
    const float* src = w + (size_t)mn * FDIM;
    uint8_t* dst = wq + ((size_t)n * CDIM + m) * FDIM;
    const int c = threadIdx.x * 8;
    f32x4 a = *(const f32x4*)(src + c);
    f32x4 b = *(const f32x4*)(src + c + 4);
    int lo = 0, hi = 0;
    lo = __builtin_amdgcn_cvt_pk_fp8_f32(a[0], a[1], lo, false);
    lo = __builtin_amdgcn_cvt_pk_fp8_f32(a[2], a[3], lo, true);
    hi = __builtin_amdgcn_cvt_pk_fp8_f32(b[0], b[1], hi, false);
    hi = __builtin_amdgcn_cvt_pk_fp8_f32(b[2], b[3], hi, true);
    int2v v; v[0] = lo; v[1] = hi;
    *(int2v*)(dst + c) = v;
}

// ---- fused DUQ GEMM, MX-fp8: 256 batch x 256 m-cols, BK=128, 8 K-iters ----
// mfma_scale_f32_16x16x128_f8f6f4, scales pinned to 1.0 (e8m0=127) -> plain
// fp8 GEMM at 2x bf16 MFMA rate, half the LDS bytes, half the barriers/K.
// A/B frag mapping (pos->k) is identical for both operands -> correct for any
// internal HW k-order. C/D layout shape-determined == 16x16x32 (verified).
__global__ __launch_bounds__(512, 2)
void duqf8(const uint8_t* __restrict__ xq, const uint8_t* __restrict__ wq,
           const float* __restrict__ csum, const float* __restrict__ cnum,
           float* __restrict__ sqp) {
    __shared__ uint8_t lsA[2][256 * 128];   // 2 x 32 KB
    __shared__ uint8_t lsB[2][256 * 128];   // 2 x 32 KB
    __shared__ float c_lds[256];
    __shared__ float red[4][256];

    const int t    = threadIdx.x;
    const int bid  = blockIdx.x;           // n*32 + rt*2 + mh
    const int n    = bid >> 5;             // class 0..99
    const int rt   = (bid >> 1) & 15;      // 256-row batch tile
    const int mh   = bid & 1;              // m half: [mh*256, +256)
    const int lane = t & 63;
    const int wid  = t >> 6;               // 0..7
    const int wm   = wid >> 2;             // 0..1 : batch rows wm*128..+127
    const int wn   = wid & 3;              // 0..3 : m cols wn*64..+63
    const int ln15 = lane & 15;
    const int kq   = lane >> 4;            // 0..3 : k-quarter (32 elems each)

    {   // centroids for this block's 256 m's
        const float inv = 1.0f / cnum[n];
        for (int i = t; i < 256; i += 512)
            c_lds[i] = csum[(size_t)(mh * 256 + i) * NCLS + n] * inv;
    }

    // staging: thread t covers row chunk*64+(t>>3), 16B at pre-swizzled col.
    // LDS[row][cb] = src[row][cb ^ (row&7)] (16B chunks, 8/row) via linear dest.
    const int st_r = t >> 3;                       // 0..63
    const int st_c = ((t & 7) ^ (st_r & 7)) * 16;  // source byte col
    const uint8_t* gA = xq + ((size_t)(rt * 256 + st_r)) * FDIM + st_c;
    const uint8_t* gB = wq + ((size_t)(n * CDIM + mh * 256 + st_r)) * FDIM + st_c;

    auto stage = [&](int it_, int bsel_) {
        const int k_ = it_ * 128;
#pragma unroll
        for (int c = 0; c < 4; ++c) {
            gl_lds16b(gA + (size_t)(c * 64) * FDIM + k_, &lsA[bsel_][c * 8192 + t * 16]);
            gl_lds16b(gB + (size_t)(c * 64) * FDIM + k_, &lsB[bsel_][c * 8192 + t * 16]);
        }
    };

    f32x4 acc[8][4];
#pragma unroll
    for (int i = 0; i < 8; ++i)
#pragma unroll
        for (int j = 0; j < 4; ++j) acc[i][j] = f32x4{0.0f, 0.0f, 0.0f, 0.0f};

    stage(0, 0);
    __syncthreads();                 // drains gl_lds; publishes c_lds; tile 0 ready

    for (int it = 0; it < 8; ++it) {
        const int bs = it & 1;
        if (it + 1 < 8) stage(it + 1, bs ^ 1);   // other buffer; readers passed last barrier
        const uint8_t* lA = lsA[bs];
        const uint8_t* lB = lsB[bs];

        // B fragments: 4 col-blocks x 32 B (two b128, chunks kq*2, kq*2+1)
        int8v bf[4];
#pragma unroll
        for (int j = 0; j < 4; ++j) {
            const int row = wn * 64 + j * 16 + ln15;
            const int sw  = (row & 7) << 4;
            int4v lo = *(const int4v*)(lB + row * 128 + (((kq * 2 + 0) << 4) ^ sw));
            int4v hi = *(const int4v*)(lB + row * 128 + (((kq * 2 + 1) << 4) ^ sw));
            union { int4v q[2]; int8v v; } u; u.q[0] = lo; u.q[1] = hi;
            bf[j] = u.v;
        }
#pragma unroll
        for (int h = 0; h < 2; ++h) {
            int8v af[4];
#pragma unroll
            for (int i = 0; i < 4; ++i) {
                const int row = wm * 128 + (h * 4 + i) * 16 + ln15;
                const int sw  = (row & 7) << 4;
                int4v lo = *(const int4v*)(lA + row * 128 + (((kq * 2 + 0) << 4) ^ sw));
                int4v hi = *(const int4v*)(lA + row * 128 + (((kq * 2 + 1) << 4) ^ sw));
                union { int4v q[2]; int8v v; } u; u.q[0] = lo; u.q[1] = hi;
                af[i] = u.v;
            }
            __builtin_amdgcn_s_setprio(1);
#pragma unroll
            for (int i = 0; i < 4; ++i)
#pragma unroll
                for (int j = 0; j < 4; ++j)
                    acc[h * 4 + i][j] = __builtin_amdgcn_mfma_scale_f32_16x16x128_f8f6f4(
                        af[i], bf[j], acc[h * 4 + i][j],
                        0, 0,          // cbsz=fp8(e4m3), blgp=fp8(e4m3)
                        0, 127,        // scale A: opsel 0, e8m0 127 = 1.0
                        0, 127);       // scale B: opsel 0, e8m0 127 = 1.0
            __builtin_amdgcn_s_setprio(0);
        }
        __syncthreads();             // vmcnt drain (full compute cover) + readers done
    }

    // epilogue: (z-c)^2 over this wave's 64 m-cols, 16-lane reduce, red, sqp
    float p[8][4];
#pragma unroll
    for (int i = 0; i < 8; ++i)
#pragma unroll
        for (int r = 0; r < 4; ++r) p[i][r] = 0.0f;
#pragma unroll
    for (int i = 0; i < 8; ++i)
#pragma unroll
        for (int j = 0; j < 4; ++j) {
            const float c = c_lds[wn * 64 + j * 16 + ln15];
#pragma unroll
            for (int r = 0; r < 4; ++r) {
                const float d = acc[i][j][r] - c;
                p[i][r] += d * d;
            }
        }
#pragma unroll
    for (int i = 0; i < 8; ++i)
#pragma unroll
        for (int r = 0; r < 4; ++r) {
            float v = p[i][r];
            v += __shfl_xor(v, 1);
            v += __shfl_xor(v, 2);
            v += __shfl_xor(v, 4);
            v += __shfl_xor(v, 8);
            p[i][r] = v;
        }
    if (ln15 == 0) {
#pragma unroll
        for (int i = 0; i < 8; ++i)
#pragma unroll
            for (int r = 0; r < 4; ++r)
                red[wn][wm * 128 + i * 16 + kq * 4 + r] = p[i][r];
    }
    __syncthreads();
    if (t < 256) {       // sum the 4 wn partials -> one value per batch row
        const float s = red[0][t] + red[1][t] + red[2][t] + red[3][t];
        sqp[(size_t)mh * (NBATCH * NCLS) + (size_t)(rt * 256 + t) * NCLS + n] = s;
    }
}

// ---- finisher: sum 2 m-half partials, scale, exp ----
__global__ void finish_kernel(const float* __restrict__ sqp, float* __restrict__ out) {
    const int i = blockIdx.x * 256 + threadIdx.x;   // 0..409599
    const float v  = sqp[i] + sqp[NBATCH * NCLS + i];
    const float lc = v * (-50.0f / 512.0f);         // -(v/512)/(2*0.1^2)
    out[i] = expf(lc);
    out[NBATCH * NCLS + i] = lc;
}

// ---- fallback (no workspace): reg-staged inline-convert variant (r1, verified) ----
__global__ __launch_bounds__(256, 2)
void duq_fallback(const float* __restrict__ x, const float* __restrict__ w,
                  const float* __restrict__ csum, const float* __restrict__ cnum,
                  float* __restrict__ out) {
    __shared__ unsigned short lsA[128 * 64];
    __shared__ unsigned short lsB[128 * 64];
    __shared__ float c_lds[CDIM];
    __shared__ float red[2][128];

    const int t = threadIdx.x;
    const int n    = blockIdx.x >> 5;
    const int tile = blockIdx.x & 31;
    const int lane = t & 63;
    const int wid  = t >> 6;
    const int wrow = wid >> 1;
    const int wcol = wid & 1;
    const int ln15 = lane & 15;
    const int hi   = lane >> 4;

    {
        const float inv = 1.0f / cnum[n];
        for (int m = t; m < CDIM; m += 256)
            c_lds[m] = csum[(size_t)m * NCLS + n] * inv;
    }

    const int srow = t >> 3;
    const int scol = (t & 7) * 8;
    const int swz  = (srow & 7) << 4;

    float p[16];
#pragma unroll
    for (int q = 0; q < 16; ++q) p[q] = 0.0f;

    for (int chunk = 0; chunk < 4; ++chunk) {
        f32x4 acc[4][4];
#pragma unroll
        for (int i = 0; i < 4; ++i)
#pragma unroll
            for (int j = 0; j < 4; ++j)
                acc[i][j] = f32x4{0.0f, 0.0f, 0.0f, 0.0f};

        for (int ks = 0; ks < 16; ++ks) {
            const int k = ks * 64;
            __syncthreads();
#pragma unroll
            for (int pp = 0; pp < 4; ++pp) {
                const int row = pp * 32 + srow;
                const float* pa = x + ((size_t)(tile * 128 + row)) * FDIM + k + scol;
                const float* pb = w + ((size_t)(chunk * 128 + row) * NCLS + n) * FDIM + k + scol;
                f32x4 a0 = *(const f32x4*)pa, a1 = *(const f32x4*)(pa + 4);
                f32x4 b0 = *(const f32x4*)pb, b1 = *(const f32x4*)(pb + 4);
                short8 ha, hb;
#pragma unroll
                for (int e = 0; e < 4; ++e) {
                    ha[e] = (short)f2bf_bits(a0[e]); ha[e + 4] = (short)f2bf_bits(a1[e]);
                    hb[e] = (short)f2bf_bits(b0[e]); hb[e + 4] = (short)f2bf_bits(b1[e]);
                }
                const int byte = (row * 128 + scol * 2) ^ swz;
                *(short8*)((char*)lsA + byte) = ha;
                *(short8*)((char*)lsB + byte) = hb;
            }
            __syncthreads();
#pragma unroll
            for (int kk = 0; kk < 2; ++kk) {
                short8 afr[4], bfr[4];
#pragma unroll
                for (int i = 0; i < 4; ++i) {
                    const int rowA = wrow * 64 + i * 16 + ln15;
                    const int ba = (rowA * 128 + (kk * 32 + hi * 8) * 2) ^ ((rowA & 7) << 4);
                    afr[i] = *(const short8*)((const char*)lsA + ba);
                    const int rowB = wcol * 64 + i * 16 + ln15;
                    const int bb = (rowB * 128 + (kk * 32 + hi * 8) * 2) ^ ((rowB & 7) << 4);
                    bfr[i] = *(const short8*)((const char*)lsB + bb);
                }
#pragma unroll
                for (int i = 0; i < 4; ++i)
#pragma unroll
                    for (int j = 0; j < 4; ++j)
                        acc[i][j] = __builtin_amdgcn_mfma_f32_16x16x32_bf16(afr[i], bfr[j], acc[i][j], 0, 0, 0);
            }
        }

#pragma unroll
        for (int i = 0; i < 4; ++i)
#pragma unroll
            for (int j = 0; j < 4; ++j) {
                const int m = chunk * 128 + wcol * 64 + j * 16 + ln15;
                const float c = c_lds[m];
#pragma unroll
                for (int r = 0; r < 4; ++r) {
                    const float d = acc[i][j][r] - c;
                    p[i * 4 + r] += d * d;
                }
            }
    }

#pragma unroll
    for (int q = 0; q < 16; ++q) {
        float v = p[q];
        v += __shfl_xor(v, 1);
        v += __shfl_xor(v, 2);
        v += __shfl_xor(v, 4);
        v += __shfl_xor(v, 8);
        p[q] = v;
    }
    __syncthreads();
    if (ln15 == 0) {
#pragma unroll
        for (int i = 0; i < 4; ++i)
#pragma unroll
            for (int r = 0; r < 4; ++r)
                red[wcol][wrow * 64 + i * 16 + hi * 4 + r] = p[i * 4 + r];
    }
    __syncthreads();
    if (t < 128) {
        const float sq = (red[0][t] + red[1][t]) * (1.0f / 512.0f);
        const float lc = -50.0f * sq;
        const size_t b = (size_t)tile * 128 + t;
        out[b * NCLS + n] = expf(lc);
        out[(size_t)NBATCH * NCLS + b * NCLS + n] = lc;
    }
}

extern "C" void kernel_launch(void* const* d_in, const int* in_sizes, int n_in,
                              void* d_out, int out_size, void* d_ws, size_t ws_size,
                              hipStream_t stream) {
    const float* x    = (const float*)d_in[0];
    const float* w    = (const float*)d_in[1];
    const float* csum = (const float*)d_in[2];
    const float* cnum = (const float*)d_in[3];
    float* out = (float*)d_out;

    const size_t nxq = (size_t)NBATCH * FDIM;          // 4.19 MB fp8
    const size_t nwq = (size_t)CDIM * NCLS * FDIM;     // 52.4 MB fp8
    const size_t need = nxq + nwq + (size_t)2 * NBATCH * NCLS * sizeof(float);

    if (ws_size >= need) {
        uint8_t* xq = (uint8_t*)d_ws;
        uint8_t* wq = xq + nxq;
        float* sqp = (float*)(wq + nwq);
        cvt_x8<<<dim3((NBATCH * FDIM) / 2048), dim3(256), 0, stream>>>(x, xq);
        cvt_w8<<<dim3(CDIM * NCLS), dim3(128), 0, stream>>>(w, wq);
        duqf8<<<dim3(NCLS * 32), dim3(512), 0, stream>>>(xq, wq, csum, cnum, sqp);
        finish_kernel<<<dim3((NBATCH * NCLS) / 256), dim3(256), 0, stream>>>(sqp, out);
    } else {
        duq_fallback<<<dim3(NCLS * 32), dim3(256), 0, stream>>>(x, w, csum, cnum, out);
    }
}